// Round 6
// baseline (1296.572 us; speedup 1.0000x reference)
//
#include <hip/hip_runtime.h>
#include <math.h>

#define TT 2048
#define UU 64
#define BB 256
#define NTHR 192   // 3 waves: wave0 = gates(i,j), wave1 = gates(f,o), wave2 = consumer

typedef float v2f __attribute__((ext_vector_type(2)));
typedef float v4f __attribute__((ext_vector_type(4)));

// Fast activations on v_exp_f32 / v_rcp_f32 (~1e-7 abs err; threshold 3.45e-6;
// validated at absmax 9.5e-7 in rounds 0-5).
__device__ __forceinline__ float frcp(float x) { return __builtin_amdgcn_rcpf(x); }
__device__ __forceinline__ float fsigmoid(float x) { return frcp(1.0f + __expf(-x)); }
__device__ __forceinline__ float ftanh(float x) { return 1.0f - 2.0f * frcp(1.0f + __expf(2.0f * x)); }

// Packed dual-FMA: a.{x,y} += h.{x,y} * w.{x,y}  (one VOP3P instruction).
__device__ __forceinline__ void pkfma(v2f& a, v2f h, v2f w) {
    asm("v_pk_fma_f32 %0, %1, %2, %0" : "+v"(a) : "v"(h), "v"(w));
}

// ROUNDS 0-5 POST-MORTEM: the RA granted r4 132 VGPRs but the kernel WANTED
// ~168 -> hidden copies/remat every step. Dur is pinned ~1100us across six
// structures because the per-step serial chain (barrier + z LDS RT + act +
// h LDS RT + matvec issue) never changed. FIX in this round:
//  (1) per-producer weights split: 64 in named v4f registers (requirement
//      ~110 regs < the 132 the RA measurably grants at waves_per_eu(1,1)),
//      64 streamed per step from a 32KB LDS table via 16 conflict-free
//      lane-strided ds_read_b128 (independent of h -> hidden under act).
//  (2) own z-pair kept in registers; only the OTHER wave's pair is read
//      after the barrier (halves the z round-trip).
//  (3) zb double-buffered by t&1 and h-ring deepened to 4 slots: the
//      write-after-read races r3-r5 survived on timing margin are now
//      structurally impossible (>=2 barriers separation).
// Numerics: chain assignment and k-order are bit-identical to r4.
//
// Wave 0: lane u owns (i,j) columns {u, 64+u} of W0. Wave 1: (f,o) columns
// {128+u, 192+u}. Per step: matvec 2 gates (16 uniform ds_read_b128 splat
// h-broadcasts + 16 reg-v4f MACs + 16 LDS-v4f MACs = 64 v_pk_fma_f32),
// write own (z,z) pair, ONE barrier, read other pair, redundant (c0,h)
// update (bit-identical in both waves), write own 4-slot splat ring.
// Wave 2 (consumer): after barrier t processes step t-1 from wave0's ring:
// 4-value 64-lane shuffle reduce + layer-1 LSTM + dense, banks output,
// coalesced flush every 64 steps. All 3 waves: exactly 1 + TT + 1 barriers.
__global__
__attribute__((amdgpu_flat_work_group_size(NTHR, NTHR)))
__attribute__((amdgpu_waves_per_eu(1, 1)))
void lstm_ts_kernel(
    const float* __restrict__ x, const float* __restrict__ W0,
    const float* __restrict__ b0, const float* __restrict__ W1,
    const float* __restrict__ b1, const float* __restrict__ Wd,
    const float* __restrict__ bd, float* __restrict__ out)
{
    __shared__ __align__(16) float xbuf[TT];              // 8 KB
    __shared__ __align__(16) v4f  WL[2][16][UU];          // 32 KB: k=32..63 weights
    __shared__ __align__(16) float ringP[2][4][2 * UU];   // 4 KB: (h,h) splat rings
    __shared__ __align__(16) v2f  zb[2][2][UU];           // 2 KB: [t&1][wave][u]
    __shared__ float red[3];

    const int tid = threadIdx.x;
    const int wid = tid >> 6;
    const int u = tid & 63;
    const int b = blockIdx.x;
    const float* xrow = x + b * TT;
    float* outrow = out + b * TT;

    // ---- prologue: stage x (+sumsq) and the LDS half of the weights ----
    float ss = 0.f;
    for (int i = tid; i < TT; i += NTHR) {
        float v = xrow[i];
        xbuf[i] = v;
        ss += v * v;
    }
    // WL[w][m][uu] = (W[32+2m][cA], W[32+2m][cB], W[33+2m][cA], W[33+2m][cB]),
    // cA = w*128+uu, cB = w*128+64+uu. Lane-strided v4f -> conflict-free reads.
    for (int idx = tid; idx < 2 * 16 * UU; idx += NTHR) {
        const int w = idx >> 10, m = (idx >> 6) & 15, uu = idx & 63;
        const int base = (33 + 2 * m) * 256 + w * 128;
        v4f e;
        e.x = W0[base + uu];       e.y = W0[base + 64 + uu];
        e.z = W0[base + 256 + uu]; e.w = W0[base + 256 + 64 + uu];
        WL[w][m][uu] = e;
    }
    #pragma unroll
    for (int m = 1; m < 64; m <<= 1) ss += __shfl_xor(ss, m, 64);
    if (u == 0) red[wid] = ss;
    if (wid < 2) {  // h_{-1} = 0: step 0 reads slot (0-1)&3 = 3
        ringP[wid][3][2 * u] = 0.f; ringP[wid][3][2 * u + 1] = 0.f;
    }
    __syncthreads();  // B0

    if (wid < 2) {
        // ============ PRODUCER wave 'wid': gate pair (i,j) or (f,o) ============
        const int go = wid * 128;  // column offset: 0 -> (i,j), 128 -> (f,o)
        const float sq = (red[0] + red[1]) + red[2];
        const float scale = 1.0f / sqrtf(fmaxf(sq, 1e-12f));  // precise, once

        // Register half: k=0..31 as 16 named v4f = 64 VGPRs (requirement now
        // fits the measured 132-reg grant). Rm = (W[2m][cA], W[2m][cB],
        // W[2m+1][cA], W[2m+1][cB]).
        #define DECLR(m) v4f R##m; { const float* r_ = W0 + (1 + 2*(m)) * 256 + go; \
            R##m.x = r_[u]; R##m.y = r_[64 + u]; \
            R##m.z = r_[256 + u]; R##m.w = r_[256 + 64 + u]; } \
            asm volatile("" : "+v"(R##m));
        DECLR(0)  DECLR(1)  DECLR(2)  DECLR(3)  DECLR(4)  DECLR(5)  DECLR(6)  DECLR(7)
        DECLR(8)  DECLR(9)  DECLR(10) DECLR(11) DECLR(12) DECLR(13) DECLR(14) DECLR(15)
        #undef DECLR

        const float wxa = W0[go + u] * scale;       // x-weight, gate a (i or f)
        const float wxb = W0[go + 64 + u] * scale;  // gate b (j or o)
        const float bca = b0[go + u], bcb = b0[go + 64 + u];

        float (*myring)[2 * UU] = ringP[wid];
        const v4f* wl = &WL[wid][0][0];
        float c0 = 0.f;

        for (int t = 0; t < TT; ++t) {
            const float xr = xbuf[t];                       // uniform broadcast
            const float* hs = myring[(t + 3) & 3];          // h_{t-1} splats

            // 4 chains; x-term folded into chain 0 (bit-identical to r4)
            v2f a0, a1 = 0.f, a2 = 0.f, a3 = 0.f;
            a0.x = fmaf(xr, wxa, bca); a0.y = fmaf(xr, wxb, bcb);

            // k2-th MAC: splat pair (h2k,h2k,h2k+1,h2k+1) x (cA,cB) weights
            #define MACR(k2, R, Ae, Ao) { \
                v4f hv_ = *(const v4f*)(hs + 4 * (k2)); \
                v2f hlo_ = __builtin_shufflevector(hv_, hv_, 0, 1); \
                v2f hhi_ = __builtin_shufflevector(hv_, hv_, 2, 3); \
                pkfma(Ae, hlo_, __builtin_shufflevector(R, R, 0, 1)); \
                pkfma(Ao, hhi_, __builtin_shufflevector(R, R, 2, 3)); \
            }
            #define MACL(k2, Ae, Ao) { \
                v4f Wv_ = wl[((k2) - 16) * UU + u]; \
                MACR(k2, Wv_, Ae, Ao) \
            }
            MACR(0,  R0,  a0, a1) MACR(1,  R1,  a2, a3)
            MACR(2,  R2,  a0, a1) MACR(3,  R3,  a2, a3)
            MACR(4,  R4,  a0, a1) MACR(5,  R5,  a2, a3)
            MACR(6,  R6,  a0, a1) MACR(7,  R7,  a2, a3)
            MACR(8,  R8,  a0, a1) MACR(9,  R9,  a2, a3)
            MACR(10, R10, a0, a1) MACR(11, R11, a2, a3)
            MACR(12, R12, a0, a1) MACR(13, R13, a2, a3)
            MACR(14, R14, a0, a1) MACR(15, R15, a2, a3)
            MACL(16, a0, a1) MACL(17, a2, a3)
            MACL(18, a0, a1) MACL(19, a2, a3)
            MACL(20, a0, a1) MACL(21, a2, a3)
            MACL(22, a0, a1) MACL(23, a2, a3)
            MACL(24, a0, a1) MACL(25, a2, a3)
            MACL(26, a0, a1) MACL(27, a2, a3)
            MACL(28, a0, a1) MACL(29, a2, a3)
            MACL(30, a0, a1) MACL(31, a2, a3)
            #undef MACL
            #undef MACR

            const v2f zown = (a0 + a1) + (a2 + a3);  // own (zA, zB) pair
            zb[t & 1][wid][u] = zown;                // ds_write_b64
            __syncthreads();                         // B(t+1): pairs exchanged

            const v2f zoth = zb[t & 1][1 - wid][u];  // only the OTHER pair
            const v2f zij = (wid == 0) ? zown : zoth;
            const v2f zfo = (wid == 0) ? zoth : zown;

            // redundant unit update -- bit-identical in both producer waves
            c0 = fsigmoid(zfo.x + 1.0f) * c0 + fsigmoid(zij.x) * ftanh(zij.y);
            const float h = fsigmoid(zfo.y) * ftanh(c0);

            v2f hh; hh.x = h; hh.y = h;
            *(v2f*)(&myring[t & 3][2 * u]) = hh;     // own 4-slot splat ring
        }
        __syncthreads();  // B(TT+1)
    } else {
        // ================= CONSUMER: layer 1 + dense + store =================
        const float w1v0 = W1[u * 4 + 0], w1v1 = W1[u * 4 + 1];
        const float w1v2 = W1[u * 4 + 2], w1v3 = W1[u * 4 + 3];
        const float w1h0 = W1[256], w1h1 = W1[257], w1h2 = W1[258], w1h3 = W1[259];
        const float b10 = b1[0], b11 = b1[1], b12 = b1[2], b13 = b1[3];
        const float wd = Wd[0], bdv = bd[0];

        float c1 = 0.f, h1 = 0.f, oval = 0.f;

        // reads wave0's ring one step lagged: slot s&3 written between B(s)
        // and B(s+1), read after B(s+1), overwritten after B(s+4) -> >=2
        // barriers of separation, structurally race-free.
        #define L1STEP(s) { \
            const float hu = ringP[0][(s) & 3][2 * u];  /* 8B stride: free */ \
            float p0 = hu * w1v0, p1 = hu * w1v1, p2 = hu * w1v2, p3 = hu * w1v3; \
            _Pragma("unroll") \
            for (int m = 1; m < 64; m <<= 1) { \
                p0 += __shfl_xor(p0, m, 64); \
                p1 += __shfl_xor(p1, m, 64); \
                p2 += __shfl_xor(p2, m, 64); \
                p3 += __shfl_xor(p3, m, 64); \
            } \
            const float z1i = p0 + fmaf(h1, w1h0, b10); \
            const float z1j = p1 + fmaf(h1, w1h1, b11); \
            const float z1f = p2 + fmaf(h1, w1h2, b12); \
            const float z1o = p3 + fmaf(h1, w1h3, b13); \
            c1 = fsigmoid(z1f + 1.0f) * c1 + fsigmoid(z1i) * ftanh(z1j); \
            h1 = fsigmoid(z1o) * ftanh(c1); \
            const float ov = fmaf(h1, wd, bdv); \
            if (((s) & 63) == u) oval = ov; \
            if (((s) & 63) == 63) outrow[((s) & ~63) + u] = oval; \
        }

        for (int t = 0; t < TT; ++t) {
            __syncthreads();  // B(t+1)
            if (t > 0) L1STEP(t - 1)
        }
        __syncthreads();  // B(TT+1) -- makes ring slot (TT-1)&3 visible
        L1STEP(TT - 1)
        #undef L1STEP
    }
}

extern "C" void kernel_launch(void* const* d_in, const int* in_sizes, int n_in,
                              void* d_out, int out_size, void* d_ws, size_t ws_size,
                              hipStream_t stream) {
    const float* x  = (const float*)d_in[0];
    const float* W0 = (const float*)d_in[1];
    const float* b0 = (const float*)d_in[2];
    const float* W1 = (const float*)d_in[3];
    const float* b1 = (const float*)d_in[4];
    const float* Wd = (const float*)d_in[5];
    const float* bd = (const float*)d_in[6];
    float* out = (float*)d_out;
    lstm_ts_kernel<<<BB, NTHR, 0, stream>>>(x, W0, b0, W1, b1, Wd, bd, out);
}